// Round 13
// baseline (76.214 us; speedup 1.0000x reference)
//
#include <hip/hip_runtime.h>
#include <hip/hip_bf16.h>
#include <hip/hip_cooperative_groups.h>

namespace cg = cooperative_groups;

#define NQ 6
#define DIM 64
#define NL 6

typedef _Float16 half8 __attribute__((ext_vector_type(8)));
typedef float f32x4 __attribute__((ext_vector_type(4)));

// ===========================================================================
// FUSED cooperative kernel (phase1: build C in blocks 0..15; grid.sync;
// phase2: grid-stride qexp over NV=batch/256 virtual blocks).
// All arithmetic verified in round 10. Works for any grid in [16, NV].
// ===========================================================================
__global__ __launch_bounds__(256, 4) void fused_qlayer(const float* __restrict__ x,
                                                       const float* __restrict__ w,
                                                       unsigned* Cws,
                                                       float* __restrict__ out,
                                                       int batch) {
    __shared__ __align__(16) unsigned Psi[256 * 36];  // 36 KB
    const int tid  = threadIdx.x;
    const int lane = tid & 63;
    const int wave = tid >> 6;

    // ================= Phase 1: build C (blocks 0..15) =================
    if (blockIdx.x < 16) {
        float* Uc = reinterpret_cast<float*>(Psi);    // [36][8] alias, pre-sync only
        if (tid < NL * NQ) {
            float phi = w[3 * tid], th = w[3 * tid + 1], om = w[3 * tid + 2];
            float ch = cosf(0.5f * th), sh = sinf(0.5f * th);
            float ap = -0.5f * (phi + om), am = -0.5f * (phi - om);
            float epr = cosf(ap), epi = sinf(ap);
            float emr = cosf(am), emi = sinf(am);
            Uc[tid * 8 + 0] =  epr * ch;
            Uc[tid * 8 + 1] =  epi * ch;
            Uc[tid * 8 + 2] = -emr * sh;
            Uc[tid * 8 + 3] =  emi * sh;
            Uc[tid * 8 + 4] =  emr * sh;
            Uc[tid * 8 + 5] =  emi * sh;
            Uc[tid * 8 + 6] =  epr * ch;
            Uc[tid * 8 + 7] = -epi * ch;
        }
        __syncthreads();

        const int col = blockIdx.x * 4 + wave;
        float re = (lane == col) ? 1.f : 0.f;
        float im = 0.f;

        #pragma unroll
        for (int l = 0; l < NL; ++l) {
            #pragma unroll
            for (int j = 0; j < NQ; ++j) {
                const int g = l * NQ + j;
                const int m = 1 << (5 - j);
                float4 uA = *(const float4*)&Uc[g * 8];
                float4 uB = *(const float4*)&Uc[g * 8 + 4];
                float pr = __shfl_xor(re, m);
                float pi = __shfl_xor(im, m);
                const bool hi = (lane & m) != 0;
                float Ar = hi ? uB.z : uA.x;
                float Ai = hi ? uB.w : uA.y;
                float Br = hi ? uB.x : uA.z;
                float Bi = hi ? uB.y : uA.w;
                float nr = Ar * re - Ai * im + Br * pr - Bi * pi;
                float ni = Ar * im + Ai * re + Br * pi + Bi * pr;
                re = nr; im = ni;
            }
            const int r = l % (NQ - 1) + 1;
            int src = lane;
            #pragma unroll
            for (int jj = NQ - 1; jj >= 0; --jj) {
                int cm = 1 << (5 - jj);
                int tm = 1 << (5 - ((jj + r) % NQ));
                src = (src & cm) ? (src ^ tm) : src;
            }
            re = __shfl(re, src);
            im = __shfl(im, src);
        }

        unsigned short* Cu = (unsigned short*)Cws;
        _Float16 hr = (_Float16)re, hi16 = (_Float16)im;
        const int s  = col >> 5;
        const int g2 = (col >> 3) & 3;
        const int e  = col & 7;
        const int t  = lane >> 4;
        const int n0 = lane & 15;
        const int dl = g2 * 16 + n0;
        const int base = (((t * 2 + s) * 64 + dl) * 4 + (e >> 1)) * 2 + (e & 1);
        Cu[base]        = __builtin_bit_cast(unsigned short, hr);
        Cu[4096 + base] = __builtin_bit_cast(unsigned short, hi16);
        __threadfence();   // device-scope release of C before grid barrier
    }

    cg::this_grid().sync();

    // ================= Phase 2: qexp, grid-stride over virtual blocks =====
    const unsigned* C = Cws;
    const int n = lane & 15;
    const int g = lane >> 4;
    const int NV = (batch + 255) >> 8;

    // persistent A-frags: coalesced frag-ordered loads
    half8 Ar[4][2], Ai[4][2];
    #pragma unroll
    for (int t = 0; t < 4; ++t)
        #pragma unroll
        for (int s = 0; s < 2; ++s) {
            int dw = ((t * 2 + s) * 64 + lane) * 4;
            Ar[t][s] = __builtin_bit_cast(half8, *(const int4*)(C + dw));
            Ai[t][s] = __builtin_bit_cast(half8, *(const int4*)(C + 2048 + dw));
        }

    const unsigned m2 = (unsigned)(g >> 1) << 31;
    const unsigned m3 = (unsigned)(g & 1) << 31;

    for (int vb = blockIdx.x; vb < NV; vb += gridDim.x) {
        const int sbase = vb * 256 + wave * 64;

        // ---- psi for sample sbase+lane, f16-packed into LDS row tid
        {
            const float2* xp = (const float2*)(x + (size_t)(sbase + lane) * NQ);
            float2 x01 = xp[0], x23 = xp[1], x45 = xp[2];
            float xa[6] = {x01.x, x01.y, x23.x, x23.y, x45.x, x45.y};
            float cs[6], sn[6];
            #pragma unroll
            for (int j = 0; j < 6; ++j) {
                float a = 1.57079632679489662f * xa[j];
                __sincosf(a, &sn[j], &cs[j]);
            }
            float a00 = cs[0] * cs[1], a01 = cs[0] * sn[1];
            float a10 = sn[0] * cs[1], a11 = sn[0] * sn[1];
            float hi[8] = {a00 * cs[2], a00 * sn[2], a01 * cs[2], a01 * sn[2],
                           a10 * cs[2], a10 * sn[2], a11 * cs[2], a11 * sn[2]};
            float b00 = cs[3] * cs[4], b01 = cs[3] * sn[4];
            float b10 = sn[3] * cs[4], b11 = sn[3] * sn[4];
            float lo[8] = {b00 * cs[5], b00 * sn[5], b01 * cs[5], b01 * sn[5],
                           b10 * cs[5], b10 * sn[5], b11 * cs[5], b11 * sn[5]};
            const int rowbase = tid * 36;
            #pragma unroll
            for (int c = 0; c < 8; ++c) {
                float h = hi[c];
                int4 d;
                d.x = __builtin_bit_cast(int, __builtin_amdgcn_cvt_pkrtz(h * lo[0], h * lo[1]));
                d.y = __builtin_bit_cast(int, __builtin_amdgcn_cvt_pkrtz(h * lo[2], h * lo[3]));
                d.z = __builtin_bit_cast(int, __builtin_amdgcn_cvt_pkrtz(h * lo[4], h * lo[5]));
                d.w = __builtin_bit_cast(int, __builtin_amdgcn_cvt_pkrtz(h * lo[6], h * lo[7]));
                *(int4*)(&Psi[rowbase + c * 4]) = d;
            }
        }
        __syncthreads();

        #pragma unroll 1
        for (int grp = 0; grp < 4; ++grp) {
            f32x4 accr[4], acci[4];
            #pragma unroll
            for (int t = 0; t < 4; ++t) { accr[t] = (f32x4)0.f; acci[t] = (f32x4)0.f; }

            #pragma unroll
            for (int s = 0; s < 2; ++s) {
                int bd = (wave * 64 + grp * 16 + n) * 36 + s * 16 + g * 4;
                half8 B = __builtin_bit_cast(half8, *(const int4*)(&Psi[bd]));
                #pragma unroll
                for (int t = 0; t < 4; ++t) {
                    accr[t] = __builtin_amdgcn_mfma_f32_16x16x32_f16(Ar[t][s], B, accr[t], 0, 0, 0);
                    acci[t] = __builtin_amdgcn_mfma_f32_16x16x32_f16(Ai[t][s], B, acci[t], 0, 0, 0);
                }
            }

            float s01[4], s23[4], a02[4], T[4];
            #pragma unroll
            for (int t = 0; t < 4; ++t) {
                float p0 = fmaf(accr[t][0], accr[t][0], acci[t][0] * acci[t][0]);
                float p1 = fmaf(accr[t][1], accr[t][1], acci[t][1] * acci[t][1]);
                float p2 = fmaf(accr[t][2], accr[t][2], acci[t][2] * acci[t][2]);
                float p3 = fmaf(accr[t][3], accr[t][3], acci[t][3] * acci[t][3]);
                s01[t] = p0 + p1;
                s23[t] = p2 + p3;
                a02[t] = p0 + p2;
                T[t]   = s01[t] + s23[t];
            }
            float u = T[0] + T[1], v = T[2] + T[3];
            float P = u + v;
            float o0 = u - v;
            float w2 = T[0] + T[2];
            float o1 = fmaf(2.f, w2, -P);
            float S01 = (s01[0] + s01[1]) + (s01[2] + s01[3]);
            float o4 = fmaf(2.f, S01, -P);
            float Sa = (a02[0] + a02[1]) + (a02[2] + a02[3]);
            float o5 = fmaf(2.f, Sa, -P);
            float o2 = __builtin_bit_cast(float, __builtin_bit_cast(unsigned, P) ^ m2);
            float o3 = __builtin_bit_cast(float, __builtin_bit_cast(unsigned, P) ^ m3);

            o0 += __shfl_xor(o0, 16); o0 += __shfl_xor(o0, 32);
            o1 += __shfl_xor(o1, 16); o1 += __shfl_xor(o1, 32);
            o2 += __shfl_xor(o2, 16); o2 += __shfl_xor(o2, 32);
            o3 += __shfl_xor(o3, 16); o3 += __shfl_xor(o3, 32);
            o4 += __shfl_xor(o4, 16); o4 += __shfl_xor(o4, 32);
            o5 += __shfl_xor(o5, 16); o5 += __shfl_xor(o5, 32);

            int sample = sbase + grp * 16 + n;
            float2* op = (float2*)(out + (size_t)sample * 6);
            if (g == 0)      { op[0] = make_float2(o0, o1); op[1] = make_float2(o2, o3); }
            else if (g == 1) { op[2] = make_float2(o4, o5); }
        }
        __syncthreads();   // protect Psi before next grid-stride iteration
    }
}

// ===========================================================================
// FALLBACK: verified round-10 two-kernel pair (17.7 us).
// ===========================================================================
__global__ __launch_bounds__(256) void build_C_kernel(const float* __restrict__ w,
                                                      unsigned short* __restrict__ Cu) {
    __shared__ __align__(16) float Uc[NL * NQ][8];
    const int tid  = threadIdx.x;
    const int lane = tid & 63;
    const int wave = tid >> 6;
    const int col  = blockIdx.x * 4 + wave;

    if (tid < NL * NQ) {
        float phi = w[3 * tid], th = w[3 * tid + 1], om = w[3 * tid + 2];
        float ch = cosf(0.5f * th), sh = sinf(0.5f * th);
        float ap = -0.5f * (phi + om), am = -0.5f * (phi - om);
        float epr = cosf(ap), epi = sinf(ap);
        float emr = cosf(am), emi = sinf(am);
        Uc[tid][0] =  epr * ch;
        Uc[tid][1] =  epi * ch;
        Uc[tid][2] = -emr * sh;
        Uc[tid][3] =  emi * sh;
        Uc[tid][4] =  emr * sh;
        Uc[tid][5] =  emi * sh;
        Uc[tid][6] =  epr * ch;
        Uc[tid][7] = -epi * ch;
    }
    __syncthreads();

    float re = (lane == col) ? 1.f : 0.f;
    float im = 0.f;

    #pragma unroll
    for (int l = 0; l < NL; ++l) {
        #pragma unroll
        for (int j = 0; j < NQ; ++j) {
            const int g = l * NQ + j;
            const int m = 1 << (5 - j);
            float4 uA = *(const float4*)&Uc[g][0];
            float4 uB = *(const float4*)&Uc[g][4];
            float pr = __shfl_xor(re, m);
            float pi = __shfl_xor(im, m);
            const bool hi = (lane & m) != 0;
            float Ar = hi ? uB.z : uA.x;
            float Ai = hi ? uB.w : uA.y;
            float Br = hi ? uB.x : uA.z;
            float Bi = hi ? uB.y : uA.w;
            float nr = Ar * re - Ai * im + Br * pr - Bi * pi;
            float ni = Ar * im + Ai * re + Br * pi + Bi * pr;
            re = nr; im = ni;
        }
        const int r = l % (NQ - 1) + 1;
        int src = lane;
        #pragma unroll
        for (int jj = NQ - 1; jj >= 0; --jj) {
            int cm = 1 << (5 - jj);
            int tm = 1 << (5 - ((jj + r) % NQ));
            src = (src & cm) ? (src ^ tm) : src;
        }
        re = __shfl(re, src);
        im = __shfl(im, src);
    }

    _Float16 hr = (_Float16)re, hi16 = (_Float16)im;
    const int s  = col >> 5;
    const int g2 = (col >> 3) & 3;
    const int e  = col & 7;
    const int t  = lane >> 4;
    const int n0 = lane & 15;
    const int dl = g2 * 16 + n0;
    const int base = (((t * 2 + s) * 64 + dl) * 4 + (e >> 1)) * 2 + (e & 1);
    Cu[base]        = __builtin_bit_cast(unsigned short, hr);
    Cu[4096 + base] = __builtin_bit_cast(unsigned short, hi16);
}

__global__ __launch_bounds__(256, 4) void qexp_mfma(const float* __restrict__ x,
                                                    const unsigned* __restrict__ C,
                                                    float* __restrict__ out,
                                                    int batch) {
    __shared__ __align__(16) unsigned Psi[256 * 36];
    const int tid  = threadIdx.x;
    const int lane = tid & 63;
    const int wave = tid >> 6;
    const int n    = lane & 15;
    const int g    = lane >> 4;
    const int sbase = blockIdx.x * 256 + wave * 64;

    half8 Ar[4][2], Ai[4][2];
    #pragma unroll
    for (int t = 0; t < 4; ++t)
        #pragma unroll
        for (int s = 0; s < 2; ++s) {
            int dw = ((t * 2 + s) * 64 + lane) * 4;
            Ar[t][s] = __builtin_bit_cast(half8, *(const int4*)(C + dw));
            Ai[t][s] = __builtin_bit_cast(half8, *(const int4*)(C + 2048 + dw));
        }

    {
        const float2* xp = (const float2*)(x + (size_t)(sbase + lane) * NQ);
        float2 x01 = xp[0], x23 = xp[1], x45 = xp[2];
        float xa[6] = {x01.x, x01.y, x23.x, x23.y, x45.x, x45.y};
        float cs[6], sn[6];
        #pragma unroll
        for (int j = 0; j < 6; ++j) {
            float a = 1.57079632679489662f * xa[j];
            __sincosf(a, &sn[j], &cs[j]);
        }
        float a00 = cs[0] * cs[1], a01 = cs[0] * sn[1];
        float a10 = sn[0] * cs[1], a11 = sn[0] * sn[1];
        float hi[8] = {a00 * cs[2], a00 * sn[2], a01 * cs[2], a01 * sn[2],
                       a10 * cs[2], a10 * sn[2], a11 * cs[2], a11 * sn[2]};
        float b00 = cs[3] * cs[4], b01 = cs[3] * sn[4];
        float b10 = sn[3] * cs[4], b11 = sn[3] * sn[4];
        float lo[8] = {b00 * cs[5], b00 * sn[5], b01 * cs[5], b01 * sn[5],
                       b10 * cs[5], b10 * sn[5], b11 * cs[5], b11 * sn[5]};
        const int rowbase = tid * 36;
        #pragma unroll
        for (int c = 0; c < 8; ++c) {
            float h = hi[c];
            int4 d;
            d.x = __builtin_bit_cast(int, __builtin_amdgcn_cvt_pkrtz(h * lo[0], h * lo[1]));
            d.y = __builtin_bit_cast(int, __builtin_amdgcn_cvt_pkrtz(h * lo[2], h * lo[3]));
            d.z = __builtin_bit_cast(int, __builtin_amdgcn_cvt_pkrtz(h * lo[4], h * lo[5]));
            d.w = __builtin_bit_cast(int, __builtin_amdgcn_cvt_pkrtz(h * lo[6], h * lo[7]));
            *(int4*)(&Psi[rowbase + c * 4]) = d;
        }
    }
    __syncthreads();

    const unsigned m2 = (unsigned)(g >> 1) << 31;
    const unsigned m3 = (unsigned)(g & 1) << 31;

    #pragma unroll 1
    for (int grp = 0; grp < 4; ++grp) {
        f32x4 accr[4], acci[4];
        #pragma unroll
        for (int t = 0; t < 4; ++t) { accr[t] = (f32x4)0.f; acci[t] = (f32x4)0.f; }

        #pragma unroll
        for (int s = 0; s < 2; ++s) {
            int bd = (wave * 64 + grp * 16 + n) * 36 + s * 16 + g * 4;
            half8 B = __builtin_bit_cast(half8, *(const int4*)(&Psi[bd]));
            #pragma unroll
            for (int t = 0; t < 4; ++t) {
                accr[t] = __builtin_amdgcn_mfma_f32_16x16x32_f16(Ar[t][s], B, accr[t], 0, 0, 0);
                acci[t] = __builtin_amdgcn_mfma_f32_16x16x32_f16(Ai[t][s], B, acci[t], 0, 0, 0);
            }
        }

        float s01[4], s23[4], a02[4], T[4];
        #pragma unroll
        for (int t = 0; t < 4; ++t) {
            float p0 = fmaf(accr[t][0], accr[t][0], acci[t][0] * acci[t][0]);
            float p1 = fmaf(accr[t][1], accr[t][1], acci[t][1] * acci[t][1]);
            float p2 = fmaf(accr[t][2], accr[t][2], acci[t][2] * acci[t][2]);
            float p3 = fmaf(accr[t][3], accr[t][3], acci[t][3] * acci[t][3]);
            s01[t] = p0 + p1;
            s23[t] = p2 + p3;
            a02[t] = p0 + p2;
            T[t]   = s01[t] + s23[t];
        }
        float u = T[0] + T[1], v = T[2] + T[3];
        float P = u + v;
        float o0 = u - v;
        float w2 = T[0] + T[2];
        float o1 = fmaf(2.f, w2, -P);
        float S01 = (s01[0] + s01[1]) + (s01[2] + s01[3]);
        float o4 = fmaf(2.f, S01, -P);
        float Sa = (a02[0] + a02[1]) + (a02[2] + a02[3]);
        float o5 = fmaf(2.f, Sa, -P);
        float o2 = __builtin_bit_cast(float, __builtin_bit_cast(unsigned, P) ^ m2);
        float o3 = __builtin_bit_cast(float, __builtin_bit_cast(unsigned, P) ^ m3);

        o0 += __shfl_xor(o0, 16); o0 += __shfl_xor(o0, 32);
        o1 += __shfl_xor(o1, 16); o1 += __shfl_xor(o1, 32);
        o2 += __shfl_xor(o2, 16); o2 += __shfl_xor(o2, 32);
        o3 += __shfl_xor(o3, 16); o3 += __shfl_xor(o3, 32);
        o4 += __shfl_xor(o4, 16); o4 += __shfl_xor(o4, 32);
        o5 += __shfl_xor(o5, 16); o5 += __shfl_xor(o5, 32);

        int sample = sbase + grp * 16 + n;
        float2* op = (float2*)(out + (size_t)sample * 6);
        if (g == 0)      { op[0] = make_float2(o0, o1); op[1] = make_float2(o2, o3); }
        else if (g == 1) { op[2] = make_float2(o4, o5); }
    }
}

extern "C" void kernel_launch(void* const* d_in, const int* in_sizes, int n_in,
                              void* d_out, int out_size, void* d_ws, size_t ws_size,
                              hipStream_t stream) {
    const float* x = (const float*)d_in[0];
    const float* w = (const float*)d_in[1];
    unsigned* C = (unsigned*)d_ws;   // 4096 dwords = 16 KB (frag-ordered Re|Im)
    float* out = (float*)d_out;
    int batch = in_sizes[0] / NQ;
    int NV = (batch + 255) / 256;    // 1024 virtual blocks

    // Negotiate cooperative grid with the runtime (host-side, capture-safe).
    int maxb = 0;
    hipError_t qe = hipOccupancyMaxActiveBlocksPerMultiprocessor(&maxb, fused_qlayer, 256, 0);
    long cap = (qe == hipSuccess) ? (long)maxb * 256 : 0;   // 256 CUs on MI355X
    int grid = (int)(cap < NV ? cap : NV);

    if (grid >= 16) {
        void* args[] = {(void*)&x, (void*)&w, (void*)&C, (void*)&out, (void*)&batch};
        hipError_t le = hipLaunchCooperativeKernel(reinterpret_cast<void*>(fused_qlayer),
                                                   dim3(grid), dim3(256), args, 0, stream);
        if (le == hipSuccess) return;
    }
    // Fallback: verified two-kernel path (round 10).
    build_C_kernel<<<16, 256, 0, stream>>>(w, (unsigned short*)C);
    qexp_mfma<<<NV, 256, 0, stream>>>(x, C, out, batch);
}

// Round 14
// 22.897 us; speedup vs baseline: 3.3286x; 3.3286x over previous
//
#include <hip/hip_runtime.h>
#include <hip/hip_bf16.h>

#define NQ 6
#define DIM 64
#define NL 6
#define MAGIC 0x5EED5EEDu

typedef _Float16 half8 __attribute__((ext_vector_type(8)));
typedef float f32x4 __attribute__((ext_vector_type(4)));

// ===========================================================================
// Single fused kernel, NO cooperative sync. Dependency "C before A-reads"
// enforced by a one-directional publish: builders (blocks 0..15) build C
// (verified round-10 wave-per-column body), threadfence, release-store a
// per-block MAGIC flag; every block stages psi into LDS first (C-independent,
// hides builder latency), then acquire-spins on the 16 flags, syncthreads,
// then loads A-frags and computes (verified round-10 body).
// Grid 1024 == co-resident capacity (36KB LDS -> 4/CU x 256 CU), so builders
// are always running -> no deadlock; bounded spin as belt-and-braces.
// Replays: flags remain MAGIC -> instant fall-through; builders rewrite
// bit-identical C (benign). First post-poison call: 0xAAAAAAAA != MAGIC.
// ===========================================================================
__global__ __launch_bounds__(256, 4) void fused_qlayer(const float* __restrict__ x,
                                                       const float* __restrict__ w,
                                                       unsigned* Cws,
                                                       float* __restrict__ out,
                                                       int batch) {
    __shared__ __align__(16) unsigned Psi[256 * 36];  // 36 KB
    const int tid  = threadIdx.x;
    const int lane = tid & 63;
    const int wave = tid >> 6;
    unsigned* flags = Cws + 8192;   // d_ws + 32KB, past the 16KB C region

    // ================= Phase 1: build C (blocks 0..15) =================
    if (blockIdx.x < 16) {
        float* Uc = reinterpret_cast<float*>(Psi);    // [36][8] alias, pre-stage only
        if (tid < NL * NQ) {
            float phi = w[3 * tid], th = w[3 * tid + 1], om = w[3 * tid + 2];
            float ch = cosf(0.5f * th), sh = sinf(0.5f * th);
            float ap = -0.5f * (phi + om), am = -0.5f * (phi - om);
            float epr = cosf(ap), epi = sinf(ap);
            float emr = cosf(am), emi = sinf(am);
            Uc[tid * 8 + 0] =  epr * ch;
            Uc[tid * 8 + 1] =  epi * ch;
            Uc[tid * 8 + 2] = -emr * sh;
            Uc[tid * 8 + 3] =  emi * sh;
            Uc[tid * 8 + 4] =  emr * sh;
            Uc[tid * 8 + 5] =  emi * sh;
            Uc[tid * 8 + 6] =  epr * ch;
            Uc[tid * 8 + 7] = -epi * ch;
        }
        __syncthreads();

        const int col = blockIdx.x * 4 + wave;
        float re = (lane == col) ? 1.f : 0.f;
        float im = 0.f;

        #pragma unroll
        for (int l = 0; l < NL; ++l) {
            #pragma unroll
            for (int j = 0; j < NQ; ++j) {
                const int g = l * NQ + j;
                const int m = 1 << (5 - j);
                float4 uA = *(const float4*)&Uc[g * 8];
                float4 uB = *(const float4*)&Uc[g * 8 + 4];
                float pr = __shfl_xor(re, m);
                float pi = __shfl_xor(im, m);
                const bool hi = (lane & m) != 0;
                float Ar = hi ? uB.z : uA.x;
                float Ai = hi ? uB.w : uA.y;
                float Br = hi ? uB.x : uA.z;
                float Bi = hi ? uB.y : uA.w;
                float nr = Ar * re - Ai * im + Br * pr - Bi * pi;
                float ni = Ar * im + Ai * re + Br * pi + Bi * pr;
                re = nr; im = ni;
            }
            const int r = l % (NQ - 1) + 1;
            int src = lane;
            #pragma unroll
            for (int jj = NQ - 1; jj >= 0; --jj) {
                int cm = 1 << (5 - jj);
                int tm = 1 << (5 - ((jj + r) % NQ));
                src = (src & cm) ? (src ^ tm) : src;
            }
            re = __shfl(re, src);
            im = __shfl(im, src);
        }

        unsigned short* Cu = (unsigned short*)Cws;
        _Float16 hr = (_Float16)re, hi16 = (_Float16)im;
        const int s  = col >> 5;
        const int g2 = (col >> 3) & 3;
        const int e  = col & 7;
        const int t  = lane >> 4;
        const int n0 = lane & 15;
        const int dl = g2 * 16 + n0;
        const int base = (((t * 2 + s) * 64 + dl) * 4 + (e >> 1)) * 2 + (e & 1);
        Cu[base]        = __builtin_bit_cast(unsigned short, hr);
        Cu[4096 + base] = __builtin_bit_cast(unsigned short, hi16);

        __threadfence();          // device-scope: C visible before flag
        __syncthreads();          // all 4 waves' stores issued+fenced
        if (tid == 0)
            __hip_atomic_store(&flags[blockIdx.x], MAGIC,
                               __ATOMIC_RELEASE, __HIP_MEMORY_SCOPE_AGENT);
    }

    // ========== Phase 2a: psi staging (C-independent, hides builders) ======
    const int n = lane & 15;
    const int g = lane >> 4;
    const int sbase = blockIdx.x * 256 + wave * 64;
    {
        const float2* xp = (const float2*)(x + (size_t)(sbase + lane) * NQ);
        float2 x01 = xp[0], x23 = xp[1], x45 = xp[2];
        float xa[6] = {x01.x, x01.y, x23.x, x23.y, x45.x, x45.y};
        float cs[6], sn[6];
        #pragma unroll
        for (int j = 0; j < 6; ++j) {
            float a = 1.57079632679489662f * xa[j];
            __sincosf(a, &sn[j], &cs[j]);
        }
        float a00 = cs[0] * cs[1], a01 = cs[0] * sn[1];
        float a10 = sn[0] * cs[1], a11 = sn[0] * sn[1];
        float hi[8] = {a00 * cs[2], a00 * sn[2], a01 * cs[2], a01 * sn[2],
                       a10 * cs[2], a10 * sn[2], a11 * cs[2], a11 * sn[2]};
        float b00 = cs[3] * cs[4], b01 = cs[3] * sn[4];
        float b10 = sn[3] * cs[4], b11 = sn[3] * sn[4];
        float lo[8] = {b00 * cs[5], b00 * sn[5], b01 * cs[5], b01 * sn[5],
                       b10 * cs[5], b10 * sn[5], b11 * cs[5], b11 * sn[5]};
        const int rowbase = tid * 36;
        #pragma unroll
        for (int c = 0; c < 8; ++c) {
            float h = hi[c];
            int4 d;
            d.x = __builtin_bit_cast(int, __builtin_amdgcn_cvt_pkrtz(h * lo[0], h * lo[1]));
            d.y = __builtin_bit_cast(int, __builtin_amdgcn_cvt_pkrtz(h * lo[2], h * lo[3]));
            d.z = __builtin_bit_cast(int, __builtin_amdgcn_cvt_pkrtz(h * lo[4], h * lo[5]));
            d.w = __builtin_bit_cast(int, __builtin_amdgcn_cvt_pkrtz(h * lo[6], h * lo[7]));
            *(int4*)(&Psi[rowbase + c * 4]) = d;
        }
    }

    // ========== Phase 2b: wait for C publication ==========================
    if (tid < 16) {
        int guard = 0;
        while (__hip_atomic_load(&flags[tid], __ATOMIC_ACQUIRE,
                                 __HIP_MEMORY_SCOPE_AGENT) != MAGIC) {
            __builtin_amdgcn_s_sleep(1);
            if (++guard > (1 << 26)) break;   // hang-guard (never trips if co-resident)
        }
    }
    __syncthreads();   // psi staged + C visible to whole block

    // ========== Phase 2c: A-frags + MFMA + epilogue (round-10 body) =======
    const unsigned* C = Cws;
    half8 Ar[4][2], Ai[4][2];
    #pragma unroll
    for (int t = 0; t < 4; ++t)
        #pragma unroll
        for (int s = 0; s < 2; ++s) {
            int dw = ((t * 2 + s) * 64 + lane) * 4;
            Ar[t][s] = __builtin_bit_cast(half8, *(const int4*)(C + dw));
            Ai[t][s] = __builtin_bit_cast(half8, *(const int4*)(C + 2048 + dw));
        }

    const unsigned m2 = (unsigned)(g >> 1) << 31;
    const unsigned m3 = (unsigned)(g & 1) << 31;

    #pragma unroll 1
    for (int grp = 0; grp < 4; ++grp) {
        f32x4 accr[4], acci[4];
        #pragma unroll
        for (int t = 0; t < 4; ++t) { accr[t] = (f32x4)0.f; acci[t] = (f32x4)0.f; }

        #pragma unroll
        for (int s = 0; s < 2; ++s) {
            int bd = (wave * 64 + grp * 16 + n) * 36 + s * 16 + g * 4;
            half8 B = __builtin_bit_cast(half8, *(const int4*)(&Psi[bd]));
            #pragma unroll
            for (int t = 0; t < 4; ++t) {
                accr[t] = __builtin_amdgcn_mfma_f32_16x16x32_f16(Ar[t][s], B, accr[t], 0, 0, 0);
                acci[t] = __builtin_amdgcn_mfma_f32_16x16x32_f16(Ai[t][s], B, acci[t], 0, 0, 0);
            }
        }

        float s01[4], s23[4], a02[4], T[4];
        #pragma unroll
        for (int t = 0; t < 4; ++t) {
            float p0 = fmaf(accr[t][0], accr[t][0], acci[t][0] * acci[t][0]);
            float p1 = fmaf(accr[t][1], accr[t][1], acci[t][1] * acci[t][1]);
            float p2 = fmaf(accr[t][2], accr[t][2], acci[t][2] * acci[t][2]);
            float p3 = fmaf(accr[t][3], accr[t][3], acci[t][3] * acci[t][3]);
            s01[t] = p0 + p1;
            s23[t] = p2 + p3;
            a02[t] = p0 + p2;
            T[t]   = s01[t] + s23[t];
        }
        float u = T[0] + T[1], v = T[2] + T[3];
        float P = u + v;
        float o0 = u - v;
        float w2 = T[0] + T[2];
        float o1 = fmaf(2.f, w2, -P);
        float S01 = (s01[0] + s01[1]) + (s01[2] + s01[3]);
        float o4 = fmaf(2.f, S01, -P);
        float Sa = (a02[0] + a02[1]) + (a02[2] + a02[3]);
        float o5 = fmaf(2.f, Sa, -P);
        float o2 = __builtin_bit_cast(float, __builtin_bit_cast(unsigned, P) ^ m2);
        float o3 = __builtin_bit_cast(float, __builtin_bit_cast(unsigned, P) ^ m3);

        o0 += __shfl_xor(o0, 16); o0 += __shfl_xor(o0, 32);
        o1 += __shfl_xor(o1, 16); o1 += __shfl_xor(o1, 32);
        o2 += __shfl_xor(o2, 16); o2 += __shfl_xor(o2, 32);
        o3 += __shfl_xor(o3, 16); o3 += __shfl_xor(o3, 32);
        o4 += __shfl_xor(o4, 16); o4 += __shfl_xor(o4, 32);
        o5 += __shfl_xor(o5, 16); o5 += __shfl_xor(o5, 32);

        int sample = sbase + grp * 16 + n;
        float2* op = (float2*)(out + (size_t)sample * 6);
        if (g == 0)      { op[0] = make_float2(o0, o1); op[1] = make_float2(o2, o3); }
        else if (g == 1) { op[2] = make_float2(o4, o5); }
    }
}

extern "C" void kernel_launch(void* const* d_in, const int* in_sizes, int n_in,
                              void* d_out, int out_size, void* d_ws, size_t ws_size,
                              hipStream_t stream) {
    const float* x = (const float*)d_in[0];
    const float* w = (const float*)d_in[1];
    unsigned* C = (unsigned*)d_ws;   // C: 16KB frag-ordered; flags at +32KB
    float* out = (float*)d_out;
    int batch = in_sizes[0] / NQ;
    int blocks = (batch + 255) / 256;   // 1024 == co-resident capacity

    fused_qlayer<<<blocks, 256, 0, stream>>>(x, w, C, out, batch);
}

// Round 15
// 17.946 us; speedup vs baseline: 4.2469x; 1.2759x over previous
//
#include <hip/hip_runtime.h>
#include <hip/hip_bf16.h>

#define NQ 6
#define DIM 64
#define NL 6

typedef _Float16 half8 __attribute__((ext_vector_type(8)));
typedef float f32x4 __attribute__((ext_vector_type(4)));

// ---------------------------------------------------------------------------
// Kernel 1 (round-10, verified): one WAVE per column; lane k holds amp k.
// Output pre-permuted in 16x16x32 MFMA frag order:
//   halfword (ri,t,s,lane,d,h) = ri*4096 + (((t*2+s)*64+lane)*4+d)*2+h,
//   frag elem (t,s,lane=(g,n),d,h) = C[row=t*16+n][kin=s*32+g*8+2d+h].
// ---------------------------------------------------------------------------
__global__ __launch_bounds__(256) void build_C_kernel(const float* __restrict__ w,
                                                      unsigned short* __restrict__ Cu) {
    __shared__ __align__(16) float Uc[NL * NQ][8];
    const int tid  = threadIdx.x;
    const int lane = tid & 63;
    const int wave = tid >> 6;
    const int col  = blockIdx.x * 4 + wave;

    if (tid < NL * NQ) {
        float phi = w[3 * tid], th = w[3 * tid + 1], om = w[3 * tid + 2];
        float ch = cosf(0.5f * th), sh = sinf(0.5f * th);
        float ap = -0.5f * (phi + om), am = -0.5f * (phi - om);
        float epr = cosf(ap), epi = sinf(ap);
        float emr = cosf(am), emi = sinf(am);
        Uc[tid][0] =  epr * ch;  // u00r
        Uc[tid][1] =  epi * ch;  // u00i
        Uc[tid][2] = -emr * sh;  // u01r
        Uc[tid][3] =  emi * sh;  // u01i
        Uc[tid][4] =  emr * sh;  // u10r
        Uc[tid][5] =  emi * sh;  // u10i
        Uc[tid][6] =  epr * ch;  // u11r
        Uc[tid][7] = -epi * ch;  // u11i
    }
    __syncthreads();

    float re = (lane == col) ? 1.f : 0.f;
    float im = 0.f;

    #pragma unroll
    for (int l = 0; l < NL; ++l) {
        #pragma unroll
        for (int j = 0; j < NQ; ++j) {
            const int g = l * NQ + j;
            const int m = 1 << (5 - j);
            float4 uA = *(const float4*)&Uc[g][0];  // u00r u00i u01r u01i
            float4 uB = *(const float4*)&Uc[g][4];  // u10r u10i u11r u11i
            float pr = __shfl_xor(re, m);
            float pi = __shfl_xor(im, m);
            const bool hi = (lane & m) != 0;
            float Ar = hi ? uB.z : uA.x;
            float Ai = hi ? uB.w : uA.y;
            float Br = hi ? uB.x : uA.z;
            float Bi = hi ? uB.y : uA.w;
            float nr = Ar * re - Ai * im + Br * pr - Bi * pi;
            float ni = Ar * im + Ai * re + Br * pi + Bi * pr;
            re = nr; im = ni;
        }
        // fused CNOT-ring permutation: new[k] = old[src(k)]
        const int r = l % (NQ - 1) + 1;
        int src = lane;
        #pragma unroll
        for (int jj = NQ - 1; jj >= 0; --jj) {
            int cm = 1 << (5 - jj);
            int tm = 1 << (5 - ((jj + r) % NQ));
            src = (src & cm) ? (src ^ tm) : src;
        }
        re = __shfl(re, src);
        im = __shfl(im, src);
    }

    // scatter into frag order (one-time 16 KB)
    _Float16 hr = (_Float16)re, hi16 = (_Float16)im;
    const int s  = col >> 5;
    const int g2 = (col >> 3) & 3;
    const int e  = col & 7;
    const int t  = lane >> 4;
    const int n0 = lane & 15;
    const int dl = g2 * 16 + n0;
    const int base = (((t * 2 + s) * 64 + dl) * 4 + (e >> 1)) * 2 + (e & 1);
    Cu[base]        = __builtin_bit_cast(unsigned short, hr);
    Cu[4096 + base] = __builtin_bit_cast(unsigned short, hi16);
}

// ---------------------------------------------------------------------------
// Kernel 2 (v6): ONE WAVE per block (64 threads, 4096 blocks), ZERO barriers.
// Psi is wave-private (reads only this wave's 64 rows) -> block barrier was
// pure overhead. Psi stride 32 dwords + slot-rotate swizzle q'=(q+row)&7
// (conflict-class unchanged; measured negligible) -> 8 KB LDS/block.
// launch_bounds(64,4): VGPR cap 128 so the 64-VGPR A-frag set stays
// register-resident across the grp loop (suspected re-load at lower caps).
// Issue order: x-loads (coldest) -> A-frags (L2-hot) -> trig -> staging.
// Arithmetic identical to round 10 (verified).
// ---------------------------------------------------------------------------
__global__ __launch_bounds__(64, 4) void qexp_mfma(const float* __restrict__ x,
                                                   const unsigned* __restrict__ C,
                                                   float* __restrict__ out,
                                                   int batch) {
    __shared__ __align__(16) unsigned Psi[64 * 32];  // 8 KB, wave-private
    const int lane = threadIdx.x;      // 0..63
    const int n    = lane & 15;
    const int g    = lane >> 4;
    const int sbase = blockIdx.x * 64;

    // 1) sample coords: issue x-loads first (deepest latency)
    const float2* xp = (const float2*)(x + (size_t)(sbase + lane) * NQ);
    float2 x01 = xp[0], x23 = xp[1], x45 = xp[2];

    // 2) persistent A-frags: coalesced frag-ordered loads (L2-hot)
    half8 Ar[4][2], Ai[4][2];
    #pragma unroll
    for (int t = 0; t < 4; ++t)
        #pragma unroll
        for (int s = 0; s < 2; ++s) {
            int dw = ((t * 2 + s) * 64 + lane) * 4;
            Ar[t][s] = __builtin_bit_cast(half8, *(const int4*)(C + dw));
            Ai[t][s] = __builtin_bit_cast(half8, *(const int4*)(C + 2048 + dw));
        }

    // 3) trig + psi staging (stride 32, rotate-swizzled slots)
    {
        float xa[6] = {x01.x, x01.y, x23.x, x23.y, x45.x, x45.y};
        float cs[6], sn[6];
        #pragma unroll
        for (int j = 0; j < 6; ++j) {
            float a = 1.57079632679489662f * xa[j];
            __sincosf(a, &sn[j], &cs[j]);
        }
        float a00 = cs[0] * cs[1], a01 = cs[0] * sn[1];
        float a10 = sn[0] * cs[1], a11 = sn[0] * sn[1];
        float hi[8] = {a00 * cs[2], a00 * sn[2], a01 * cs[2], a01 * sn[2],
                       a10 * cs[2], a10 * sn[2], a11 * cs[2], a11 * sn[2]};
        float b00 = cs[3] * cs[4], b01 = cs[3] * sn[4];
        float b10 = sn[3] * cs[4], b11 = sn[3] * sn[4];
        float lo[8] = {b00 * cs[5], b00 * sn[5], b01 * cs[5], b01 * sn[5],
                       b10 * cs[5], b10 * sn[5], b11 * cs[5], b11 * sn[5]};
        const int rowbase = lane * 32;
        #pragma unroll
        for (int c = 0; c < 8; ++c) {
            float h = hi[c];
            int4 d;
            d.x = __builtin_bit_cast(int, __builtin_amdgcn_cvt_pkrtz(h * lo[0], h * lo[1]));
            d.y = __builtin_bit_cast(int, __builtin_amdgcn_cvt_pkrtz(h * lo[2], h * lo[3]));
            d.z = __builtin_bit_cast(int, __builtin_amdgcn_cvt_pkrtz(h * lo[4], h * lo[5]));
            d.w = __builtin_bit_cast(int, __builtin_amdgcn_cvt_pkrtz(h * lo[6], h * lo[7]));
            *(int4*)(&Psi[rowbase + ((c + lane) & 7) * 4]) = d;
        }
    }
    // no barrier: wave-coherent LDS; compiler inserts lgkmcnt before reads

    const unsigned m2 = (unsigned)(g >> 1) << 31;   // k_out bit3 sign (j=2)
    const unsigned m3 = (unsigned)(g & 1) << 31;    // k_out bit2 sign (j=3)

    #pragma unroll 1
    for (int grp = 0; grp < 4; ++grp) {
        f32x4 accr[4], acci[4];
        #pragma unroll
        for (int t = 0; t < 4; ++t) { accr[t] = (f32x4)0.f; acci[t] = (f32x4)0.f; }

        #pragma unroll
        for (int s = 0; s < 2; ++s) {
            int row = grp * 16 + n;
            int bd = row * 32 + (((s * 4 + g) + row) & 7) * 4;
            half8 B = __builtin_bit_cast(half8, *(const int4*)(&Psi[bd]));
            #pragma unroll
            for (int t = 0; t < 4; ++t) {
                accr[t] = __builtin_amdgcn_mfma_f32_16x16x32_f16(Ar[t][s], B, accr[t], 0, 0, 0);
                acci[t] = __builtin_amdgcn_mfma_f32_16x16x32_f16(Ai[t][s], B, acci[t], 0, 0, 0);
            }
        }

        // factored sign-sums: k_out = t*16 + g*4 + i
        float s01[4], s23[4], a02[4], T[4];
        #pragma unroll
        for (int t = 0; t < 4; ++t) {
            float p0 = fmaf(accr[t][0], accr[t][0], acci[t][0] * acci[t][0]);
            float p1 = fmaf(accr[t][1], accr[t][1], acci[t][1] * acci[t][1]);
            float p2 = fmaf(accr[t][2], accr[t][2], acci[t][2] * acci[t][2]);
            float p3 = fmaf(accr[t][3], accr[t][3], acci[t][3] * acci[t][3]);
            s01[t] = p0 + p1;
            s23[t] = p2 + p3;
            a02[t] = p0 + p2;
            T[t]   = s01[t] + s23[t];
        }
        float u = T[0] + T[1], v = T[2] + T[3];
        float P = u + v;
        float o0 = u - v;                      // j=0: sign = bit5 = t&2
        float w2 = T[0] + T[2];
        float o1 = fmaf(2.f, w2, -P);          // j=1: sign = bit4 = t&1
        float S01 = (s01[0] + s01[1]) + (s01[2] + s01[3]);
        float o4 = fmaf(2.f, S01, -P);         // j=4: sign = bit1 = i&2
        float Sa = (a02[0] + a02[1]) + (a02[2] + a02[3]);
        float o5 = fmaf(2.f, Sa, -P);          // j=5: sign = bit0 = i&1
        float o2 = __builtin_bit_cast(float, __builtin_bit_cast(unsigned, P) ^ m2);
        float o3 = __builtin_bit_cast(float, __builtin_bit_cast(unsigned, P) ^ m3);

        // fold the 4 k-groups (lanes n, n+16, n+32, n+48)
        o0 += __shfl_xor(o0, 16); o0 += __shfl_xor(o0, 32);
        o1 += __shfl_xor(o1, 16); o1 += __shfl_xor(o1, 32);
        o2 += __shfl_xor(o2, 16); o2 += __shfl_xor(o2, 32);
        o3 += __shfl_xor(o3, 16); o3 += __shfl_xor(o3, 32);
        o4 += __shfl_xor(o4, 16); o4 += __shfl_xor(o4, 32);
        o5 += __shfl_xor(o5, 16); o5 += __shfl_xor(o5, 32);

        int sample = sbase + grp * 16 + n;
        float2* op = (float2*)(out + (size_t)sample * 6);
        if (g == 0)      { op[0] = make_float2(o0, o1); op[1] = make_float2(o2, o3); }
        else if (g == 1) { op[2] = make_float2(o4, o5); }
    }
}

extern "C" void kernel_launch(void* const* d_in, const int* in_sizes, int n_in,
                              void* d_out, int out_size, void* d_ws, size_t ws_size,
                              hipStream_t stream) {
    const float* x = (const float*)d_in[0];
    const float* w = (const float*)d_in[1];
    unsigned* C = (unsigned*)d_ws;   // 4096 dwords = 16 KB (frag-ordered Re|Im)
    float* out = (float*)d_out;
    const int batch = in_sizes[0] / NQ;

    build_C_kernel<<<16, 256, 0, stream>>>(w, (unsigned short*)C);
    const int blocks = (batch + 63) / 64;   // 4096 blocks x 64 threads
    qexp_mfma<<<blocks, 64, 0, stream>>>(x, C, out, batch);
}